// Round 14
// baseline (70.632 us; speedup 1.0000x reference)
//
#include <hip/hip_runtime.h>

#define IMG_H 256
#define IMG_W 256
#define ROWS 16
#define NIMG 128
#define NWAVES 4096   // img x 16 row-strips x 2 quarter-pairs; 2 strips per wave

__device__ __forceinline__ float ssim1(float mu1, float mu2, float spp, float stt, float spt) {
    const float C1 = 1e-4f, C2 = 9e-4f;
    float mu1s = mu1 * mu1, mu2s = mu2 * mu2, mu12 = mu1 * mu2;
    float s1 = spp - mu1s, s2 = stt - mu2s, s12 = spt - mu12;
    float num = (2.f * mu12 + C1) * (2.f * s12 + C2);
    float den = (mu1s + mu2s + C1) * (s1 + s2 + C2);
    return num * __builtin_amdgcn_rcpf(den);
}

// H-first separable SSIM, LDS-row family, DUAL-STRIP ILP (R14).
// R12/R13 lesson: VALU issue time is ~20-23us; TLP never lifted duty past
// ~44% because co-resident waves run the same stream and stall in phase on
// the in-step ds_read->lgkm->HC chain. R14 gives each wave TWO independent
// 16x64 strips (same rows, adjacent col-quarters, private LDS regions) and
// interleaves them: stageA,readA, stageB,readB, gloads, HC_A,out_A,
// HC_B,out_B. Each stream's LDS-read latency is covered by the OTHER
// stream's issue traffic -> single-wave duty ~2x; TLP only supplements.
// Same-wave DS is in-order (R8-R13-proven), no barriers, 1-step global
// prefetch, mod-7 windows, rolled 2x7 steady loop (VGPR-proven shape).
template<int ATOMIC>
__global__ __launch_bounds__(256) void ssim_main(
    const float* __restrict__ pred,
    const float* __restrict__ targ,
    const float* __restrict__ window,
    float* __restrict__ wsum)
{
    __shared__ float2 sbuf[8][72];    // [wave*2+strip][col c at idx c-X0+4]

    const int lane = threadIdx.x & 63;
    const int wid  = threadIdx.x >> 6;
    const int gw   = blockIdx.x * 4 + wid;   // 0..4095
    const int n    = gw >> 5;                // image
    const int r    = gw & 31;
    const int r0   = (r >> 1) * ROWS;        // strip start row
    const int qh   = r & 1;                  // quarter-pair selector
    const int X0a  = qh << 7;                // strip A cols: 0 or 128
    const int X0b  = X0a + 64;               // strip B cols: 64 or 192

    // exact 1D gaussian from w2d row 3: g[j] = w[21+j] / sum
    float g[7];
    {
        float sum = 0.f;
#pragma unroll
        for (int j = 0; j < 7; ++j) { g[j] = window[21 + j]; sum += g[j]; }
        float inv = 1.f / sum;
#pragma unroll
        for (int j = 0; j < 7; ++j) g[j] *= inv;
    }

    const float* pimg = pred + (size_t)n * (IMG_H * IMG_W);
    const float* timg = targ + (size_t)n * (IMG_H * IMG_W);
    const int moA = X0a + lane;
    const int moB = X0b + lane;

    // halo duty, lanes 0..5; LDS index shared, global col per strip
    int hidx = 0, hoff = 0;
    if (lane < 3)      { hidx = lane + 1;  hoff = lane - 3; }   // left cols X0-3..X0-1
    else if (lane < 6) { hidx = lane + 65; hoff = lane + 61; }  // right cols X0+64..X0+66
    const int hcolA = X0a + hoff, hcolB = X0b + hoff;
    const bool hvA = (lane < 6) && ((unsigned)hcolA < (unsigned)IMG_W);
    const bool hvB = (lane < 6) && ((unsigned)hcolB < (unsigned)IMG_W);

    // mod-7 register windows, one set per strip (all static indices)
    float AmuA[7], AtuA[7], AppA[7], AttA[7], AptA[7];
    float AmuB[7], AtuB[7], AppB[7], AttB[7], AptB[7];
    float acc = 0.f;

    float PrA, TrA, PrB, TrB;    // global prefetch regs
    float2 HrA, HrB;

    float2* swA       = sbuf[wid * 2];
    float2* swB       = sbuf[wid * 2 + 1];
    const float2* sbA = swA;
    const float2* sbB = swB;

#define GLOADD(J) { \
    const int j_ = (J); \
    PrA = 0.f; TrA = 0.f; PrB = 0.f; TrB = 0.f; \
    HrA = make_float2(0.f, 0.f); HrB = HrA; \
    if ((unsigned)j_ < (unsigned)IMG_H) { \
        const int rb = j_ * IMG_W; \
        PrA = pimg[rb + moA]; TrA = timg[rb + moA]; \
        PrB = pimg[rb + moB]; TrB = timg[rb + moB]; \
        if (hvA) { HrA.x = pimg[rb + hcolA]; HrA.y = timg[rb + hcolA]; } \
        if (hvB) { HrB.x = pimg[rb + hcolB]; HrB.y = timg[rb + hcolB]; } \
    } }

#define TAP(K, Q) { \
    float p = (Q).x, t = (Q).y; \
    float wp = g[K] * p, wt = g[K] * t; \
    m_  = fmaf(g[K], p, m_);  u_  = fmaf(g[K], t, u_); \
    pp_ = fmaf(wp, p, pp_);   tt_ = fmaf(wt, t, tt_); \
    pt_ = fmaf(wp, t, pt_); }

#define HCQ(SLOT, MU, TU, PP, TT, PT, Q0, Q1, Q2, Q3, Q4, Q5, Q6) { \
    float m_ = 0.f, u_ = 0.f, pp_ = 0.f, tt_ = 0.f, pt_ = 0.f; \
    TAP(0, Q0) TAP(1, Q1) TAP(2, Q2) TAP(3, Q3) \
    TAP(4, Q4) TAP(5, Q5) TAP(6, Q6) \
    MU[SLOT] = m_; TU[SLOT] = u_; PP[SLOT] = pp_; \
    TT[SLOT] = tt_; PT[SLOT] = pt_; }

#define VD(A_, U) ( fmaf(g[6], A_[((U)+6)%7], fmaf(g[5], A_[((U)+5)%7], \
    fmaf(g[4], A_[((U)+4)%7], fmaf(g[3], A_[((U)+3)%7], fmaf(g[2], A_[((U)+2)%7], \
    fmaf(g[1], A_[((U)+1)%7], g[0] * A_[(U)%7])))))) )

#define OUTQ(U, MU, TU, PP, TT, PT) { \
    float m1 = VD(MU,U), m2 = VD(TU,U), pp = VD(PP,U), \
          tt = VD(TT,U), pt = VD(PT,U); \
    acc += ssim1(m1, m2, pp, tt, pt); }

// dual step for row j = r0+JOFF. Entry: Pr*/Tr*/Hr* hold row j.
// Order: stageA,readA | stageB,readB | gload j+1 | HC_A,out_A | HC_B,out_B.
// readA->HC_A covered by B's DS+VMEM issue; readB->HC_B by HC_A+out_A.
#define STEPD(SLOT, JOFF, HASOUT, U, DOLOAD) { \
    swA[lane + 4] = make_float2(PrA, TrA); \
    if (lane < 6) swA[hidx] = HrA; \
    float2 a0 = sbA[lane + 1], a1 = sbA[lane + 2], a2 = sbA[lane + 3], \
           a3 = sbA[lane + 4], a4 = sbA[lane + 5], a5 = sbA[lane + 6], \
           a6 = sbA[lane + 7]; \
    swB[lane + 4] = make_float2(PrB, TrB); \
    if (lane < 6) swB[hidx] = HrB; \
    float2 b0 = sbB[lane + 1], b1 = sbB[lane + 2], b2 = sbB[lane + 3], \
           b3 = sbB[lane + 4], b4 = sbB[lane + 5], b5 = sbB[lane + 6], \
           b6 = sbB[lane + 7]; \
    if (DOLOAD) { GLOADD(r0 + (JOFF) + 1); } \
    HCQ(SLOT, AmuA, AtuA, AppA, AttA, AptA, a0, a1, a2, a3, a4, a5, a6) \
    if (HASOUT) { OUTQ(U, AmuA, AtuA, AppA, AttA, AptA) } \
    HCQ(SLOT, AmuB, AtuB, AppB, AttB, AptB, b0, b1, b2, b3, b4, b5, b6) \
    if (HASOUT) { OUTQ(U, AmuB, AtuB, AppB, AttB, AptB) } }

    // prologue: prefetch first halo row (both strips)
    GLOADD(r0 - 3);

    // rows r0-3 .. r0+2 -> slots 0..5 (no output yet)
    STEPD(0, -3, 0, 0, 1)
    STEPD(1, -2, 0, 0, 1)
    STEPD(2, -1, 0, 0, 1)
    STEPD(3,  0, 0, 0, 1)
    STEPD(4,  1, 0, 0, 1)
    STEPD(5,  2, 0, 0, 1)

    // 2 x 7 steady-state steps (slot pattern repeats mod 7); rolled loop
    // keeps the allocator lean (R9/R11/R12-proven)
#pragma unroll 1
    for (int jb = 0; jb < 2; ++jb) {
        const int base = 3 + jb * 7;
        STEPD(6, base,     1, 0, 1)
        STEPD(0, base + 1, 1, 1, 1)
        STEPD(1, base + 2, 1, 2, 1)
        STEPD(2, base + 3, 1, 3, 1)
        STEPD(3, base + 4, 1, 4, 1)
        STEPD(4, base + 5, 1, 5, 1)
        STEPD(5, base + 6, 1, 6, 1)
    }
    // tail: rows r0+17, r0+18 -> output rows r0+14, r0+15
    STEPD(6, 17, 1, 0, 1)
    STEPD(0, 18, 1, 1, 0)

#undef GLOADD
#undef TAP
#undef HCQ
#undef VD
#undef OUTQ
#undef STEPD

    // wave reduce, one write (or atomic) per wave
#pragma unroll
    for (int off = 32; off > 0; off >>= 1)
        acc += __shfl_xor(acc, off, 64);
    if (lane == 0) {
        if (ATOMIC) atomicAdd(&wsum[0], acc);
        else        wsum[gw] = acc;
    }
}

// deterministic f64 tree-reduce of the 4096 per-wave partials
__global__ __launch_bounds__(256) void ssim_final_arr(
    const float* __restrict__ ws, float* __restrict__ out)
{
    __shared__ double sred[4];
    double sm = 0.0;
#pragma unroll
    for (int k = 0; k < NWAVES / 256; ++k)
        sm += (double)ws[threadIdx.x + k * 256];
#pragma unroll
    for (int off = 32; off > 0; off >>= 1)
        sm += __shfl_down(sm, off, 64);
    const int lane = threadIdx.x & 63, wid = threadIdx.x >> 6;
    if (lane == 0) sred[wid] = sm;
    __syncthreads();
    if (threadIdx.x == 0) {
        double tot = sred[0] + sred[1] + sred[2] + sred[3];
        out[0] = (float)(1.0 - tot * (1.0 / (128.0 * 256.0 * 256.0)));
    }
}

__global__ void ssim_final_sc(const float* __restrict__ ws, float* __restrict__ out)
{
    out[0] = 1.0f - ws[0] * (1.0f / (128.0f * 256.0f * 256.0f));
}

extern "C" void kernel_launch(void* const* d_in, const int* in_sizes, int n_in,
                              void* d_out, int out_size, void* d_ws, size_t ws_size,
                              hipStream_t stream)
{
    const float* pred   = (const float*)d_in[0];
    const float* targ   = (const float*)d_in[1];
    const float* window = (const float*)d_in[2];
    float* out = (float*)d_out;
    float* ws  = (float*)d_ws;

    if (ws_size >= NWAVES * sizeof(float)) {
        // every ws slot is written by the grid each call: no memset needed
        ssim_main<0><<<NWAVES / 4, 256, 0, stream>>>(pred, targ, window, ws);
        ssim_final_arr<<<1, 256, 0, stream>>>(ws, out);
    } else {
        hipMemsetAsync(ws, 0, sizeof(float), stream);
        ssim_main<1><<<NWAVES / 4, 256, 0, stream>>>(pred, targ, window, ws);
        ssim_final_sc<<<1, 1, 0, stream>>>(ws, out);
    }
    (void)in_sizes; (void)n_in; (void)out_size;
}

// Round 15
// 46.826 us; speedup vs baseline: 1.5084x; 1.5084x over previous
//
#include <hip/hip_runtime.h>

#define IMG_H 256
#define IMG_W 256
#define ROWS 32
#define NIMG 128
#define NWAVES (NIMG * 8 * 4)   // 4096: img x 8 row-strips(32) x 4 col-quarters

__device__ __forceinline__ float ssim1(float mu1, float mu2, float spp, float stt, float spt) {
    const float C1 = 1e-4f, C2 = 9e-4f;
    float mu1s = mu1 * mu1, mu2s = mu2 * mu2, mu12 = mu1 * mu2;
    float s1 = spp - mu1s, s2 = stt - mu2s, s12 = spt - mu12;
    float num = (2.f * mu12 + C1) * (2.f * s12 + C2);
    float den = (mu1s + mu2s + C1) * (s1 + s2 + C2);
    return num * __builtin_amdgcn_rcpf(den);
}

// H-first separable SSIM, LDS-row family (R15 = R12 with ROWS 16->32).
// Series model: R12 is latency-bound (DS ~16us, VALU ~17us pipe time vs
// 44.6us wall); no single pipe saturated, ~2 true waves/SIMD each ~40%
// duty. Only residency-neutral lever left: fewer instructions per output
// row. ROWS=32 cuts prologue amortization 22/16 -> 38/32 = -13.6% of all
// instruction traffic at IDENTICAL VGPR (window regs don't scale with
// ROWS) and identical step structure (single-buffer in-order same-wave DS,
// no barriers, 1-step global prefetch, mod-7 window, rolled steady loop).
template<int ATOMIC>
__global__ __launch_bounds__(256) void ssim_main(
    const float* __restrict__ pred,
    const float* __restrict__ targ,
    const float* __restrict__ window,
    float* __restrict__ wsum)
{
    __shared__ float2 sbuf[4][72];    // [wave][col c at idx c-X0+4]

    const int lane = threadIdx.x & 63;
    const int wid  = threadIdx.x >> 6;
    const int gw   = blockIdx.x * 4 + wid;   // 0..4095
    const int n    = gw >> 5;                // image
    const int r    = gw & 31;
    const int r0   = (r >> 2) * ROWS;        // strip start row (8 strips)
    const int X0   = (r & 3) << 6;           // col quarter: 0/64/128/192

    // exact 1D gaussian from w2d row 3: g[j] = w[21+j] / sum
    float g[7];
    {
        float sum = 0.f;
#pragma unroll
        for (int j = 0; j < 7; ++j) { g[j] = window[21 + j]; sum += g[j]; }
        float inv = 1.f / sum;
#pragma unroll
        for (int j = 0; j < 7; ++j) g[j] *= inv;
    }

    const float* pimg = pred + (size_t)n * (IMG_H * IMG_W);
    const float* timg = targ + (size_t)n * (IMG_H * IMG_W);
    const int mo = X0 + lane;         // own column

    // halo duty, lanes 0..5: left cols X0-3..X0-1 (idx 1..3),
    // right cols X0+64..X0+66 (idx 68..70)
    int hidx = 0, hcol = 0;
    if (lane < 3)      { hidx = lane + 1;  hcol = X0 - 3 + lane;  }
    else if (lane < 6) { hidx = lane + 65; hcol = X0 + 61 + lane; }
    const bool hv = (lane < 6) && ((unsigned)hcol < (unsigned)IMG_W);

    // mod-7 register window: 1 col x 5 quantities x 7 slots (static idx)
    float Amu[7], Atu[7], App[7], Att[7], Apt[7];
    float acc = 0.f;

    float Pr, Tr;        // prefetch regs for own column
    float2 Hr;           // prefetch reg for halo col (p,t)

#define GLOAD(J) { \
    const int j_ = (J); \
    Pr = 0.f; Tr = 0.f; Hr = make_float2(0.f, 0.f); \
    if ((unsigned)j_ < (unsigned)IMG_H) { \
        Pr = pimg[j_ * IMG_W + mo]; \
        Tr = timg[j_ * IMG_W + mo]; \
        if (hv) { \
            Hr.x = pimg[j_ * IMG_W + hcol]; \
            Hr.y = timg[j_ * IMG_W + hcol]; \
        } \
    } }

#define TAP(K, Q) { \
    float p = (Q).x, t = (Q).y; \
    float wp = g[K] * p, wt = g[K] * t; \
    m_  = fmaf(g[K], p, m_);  u_  = fmaf(g[K], t, u_); \
    pp_ = fmaf(wp, p, pp_);   tt_ = fmaf(wt, t, tt_); \
    pt_ = fmaf(wp, t, pt_); }

#define VD(A_, U) ( fmaf(g[6], A_[((U)+6)%7], fmaf(g[5], A_[((U)+5)%7], \
    fmaf(g[4], A_[((U)+4)%7], fmaf(g[3], A_[((U)+3)%7], fmaf(g[2], A_[((U)+2)%7], \
    fmaf(g[1], A_[((U)+1)%7], g[0] * A_[(U)%7])))))) )

#define OUTR(U) { \
    float m1 = VD(Amu,U), m2 = VD(Atu,U), pp = VD(App,U), tt = VD(Att,U), pt = VD(Apt,U); \
    acc += ssim1(m1, m2, pp, tt, pt); }

// step for row j = r0+JOFF. Entry: Pr/Tr/Hr hold row j (loaded last step).
// stage row j -> read 7-col neighborhood -> prefetch row j+1 -> H-conv ->
// optional output row. Single buffer: same-wave DS is in-order.
#define STEPX(SLOT, JOFF, HASOUT, U, DOLOAD) { \
    { \
        float2* sw = sbuf[wid]; \
        sw[lane + 4] = make_float2(Pr, Tr); \
        if (lane < 6) sw[hidx] = Hr; \
    } \
    const float2* sb = sbuf[wid]; \
    float2 q0 = sb[lane + 1], q1 = sb[lane + 2], q2 = sb[lane + 3]; \
    float2 q3 = sb[lane + 4], q4 = sb[lane + 5], q5 = sb[lane + 6]; \
    float2 q6 = sb[lane + 7]; \
    if (DOLOAD) { GLOAD(r0 + (JOFF) + 1); } \
    { \
        float m_ = 0.f, u_ = 0.f, pp_ = 0.f, tt_ = 0.f, pt_ = 0.f; \
        TAP(0, q0) TAP(1, q1) TAP(2, q2) TAP(3, q3) TAP(4, q4) \
        TAP(5, q5) TAP(6, q6) \
        Amu[SLOT] = m_; Atu[SLOT] = u_; App[SLOT] = pp_; \
        Att[SLOT] = tt_; Apt[SLOT] = pt_; \
    } \
    if (HASOUT) { OUTR(U) } }

    // prologue: prefetch first halo row
    GLOAD(r0 - 3);

    // rows r0-3 .. r0+2 -> slots 0..5 (no output yet)
    STEPX(0, -3, 0, 0, 1)
    STEPX(1, -2, 0, 0, 1)
    STEPX(2, -1, 0, 0, 1)
    STEPX(3,  0, 0, 0, 1)
    STEPX(4,  1, 0, 0, 1)
    STEPX(5,  2, 0, 0, 1)

    // 4 x 7 steady-state steps (slot pattern repeats mod 7); rolled loop
    // keeps the allocator lean (R9/R11/R12-proven)
#pragma unroll 1
    for (int jb = 0; jb < 4; ++jb) {
        const int base = 3 + jb * 7;
        STEPX(6, base,     1, 0, 1)
        STEPX(0, base + 1, 1, 1, 1)
        STEPX(1, base + 2, 1, 2, 1)
        STEPX(2, base + 3, 1, 3, 1)
        STEPX(3, base + 4, 1, 4, 1)
        STEPX(4, base + 5, 1, 5, 1)
        STEPX(5, base + 6, 1, 6, 1)
    }
    // tail: input rows r0+31..r0+34 -> output rows r0+28..r0+31
    // (rows past r0+33 are OOB-guarded zero prefetches; harmless)
    STEPX(6, 31, 1, 0, 1)
    STEPX(0, 32, 1, 1, 1)
    STEPX(1, 33, 1, 2, 1)
    STEPX(2, 34, 1, 3, 0)

#undef GLOAD
#undef TAP
#undef VD
#undef OUTR
#undef STEPX

    // wave reduce, one write (or atomic) per wave
#pragma unroll
    for (int off = 32; off > 0; off >>= 1)
        acc += __shfl_xor(acc, off, 64);
    if (lane == 0) {
        if (ATOMIC) atomicAdd(&wsum[0], acc);
        else        wsum[gw] = acc;
    }
}

// deterministic f64 tree-reduce of the 4096 per-wave partials
__global__ __launch_bounds__(256) void ssim_final_arr(
    const float* __restrict__ ws, float* __restrict__ out)
{
    __shared__ double sred[4];
    double sm = 0.0;
#pragma unroll
    for (int k = 0; k < NWAVES / 256; ++k)
        sm += (double)ws[threadIdx.x + k * 256];
#pragma unroll
    for (int off = 32; off > 0; off >>= 1)
        sm += __shfl_down(sm, off, 64);
    const int lane = threadIdx.x & 63, wid = threadIdx.x >> 6;
    if (lane == 0) sred[wid] = sm;
    __syncthreads();
    if (threadIdx.x == 0) {
        double tot = sred[0] + sred[1] + sred[2] + sred[3];
        out[0] = (float)(1.0 - tot * (1.0 / (128.0 * 256.0 * 256.0)));
    }
}

__global__ void ssim_final_sc(const float* __restrict__ ws, float* __restrict__ out)
{
    out[0] = 1.0f - ws[0] * (1.0f / (128.0f * 256.0f * 256.0f));
}

extern "C" void kernel_launch(void* const* d_in, const int* in_sizes, int n_in,
                              void* d_out, int out_size, void* d_ws, size_t ws_size,
                              hipStream_t stream)
{
    const float* pred   = (const float*)d_in[0];
    const float* targ   = (const float*)d_in[1];
    const float* window = (const float*)d_in[2];
    float* out = (float*)d_out;
    float* ws  = (float*)d_ws;

    if (ws_size >= NWAVES * sizeof(float)) {
        // every ws slot is written by the grid each call: no memset needed
        ssim_main<0><<<NWAVES / 4, 256, 0, stream>>>(pred, targ, window, ws);
        ssim_final_arr<<<1, 256, 0, stream>>>(ws, out);
    } else {
        hipMemsetAsync(ws, 0, sizeof(float), stream);
        ssim_main<1><<<NWAVES / 4, 256, 0, stream>>>(pred, targ, window, ws);
        ssim_final_sc<<<1, 1, 0, stream>>>(ws, out);
    }
    (void)in_sizes; (void)n_in; (void)out_size;
}